// Round 11
// baseline (587.698 us; speedup 1.0000x reference)
//
#include <hip/hip_runtime.h>

#define WS7    7
#define SHIFT3 3
#define NHEAD  6
#define CCH    192
#define HDIM   32
#define HH56   56
#define LTOK   (HH56*HH56)      // 3136
#define NWIN   64
#define NBATCH 32
#define NWTOT  (NBATCH*NWIN)    // 2048
#define LW     49
#define MTOK   (NWTOT*LW)       // 100352

typedef unsigned short u16;
typedef unsigned int   u32;
typedef __bf16 b16;
typedef b16   b16x8 __attribute__((ext_vector_type(8)));
typedef u16   u16x8 __attribute__((ext_vector_type(8)));
typedef float f32x4 __attribute__((ext_vector_type(4)));

__device__ __forceinline__ float b2f(u16 u) {
    u32 x = ((u32)u) << 16;
    return __builtin_bit_cast(float, x);
}
__device__ __forceinline__ u16 f2b(float f) {
    u32 x = __builtin_bit_cast(u32, f);
    u32 r = x + 0x7FFFu + ((x >> 16) & 1u);
    return (u16)(r >> 16);
}
__device__ __forceinline__ float gelu_exact(float x) {
    return 0.5f * x * (1.0f + erff(x * 0.7071067811865475f));
}

// token m (window-order) -> (b, l) image order (bijection)
__device__ __forceinline__ int map_token(int m, int &b) {
    int widx = m / LW, p = m - widx * LW;
    b = widx >> 6;
    int wloc = widx & 63;
    int wh = wloc >> 3, ww = wloc & 7;
    int i = p / WS7, j = p - i * WS7;
    int gh = wh * WS7 + i + SHIFT3; if (gh >= HH56) gh -= HH56;
    int gw = ww * WS7 + j + SHIFT3; if (gw >= HH56) gw -= HH56;
    return gh * HH56 + gw;
}

// ---- dtype probe: flag=1 if x is fp32 storage, 0 if bf16 storage.
__global__ __launch_bounds__(1024) void probe_kernel(const u16* __restrict__ x, int* flag) {
    __shared__ int ch, cz;
    if (threadIdx.x == 0) { ch = 0; cz = 0; }
    __syncthreads();
    int i = threadIdx.x * 16;
    u16x8 a = *(const u16x8*)(x + i);
    u16x8 b = *(const u16x8*)(x + i + 8);
    int h = 0, z = 0;
    #pragma unroll
    for (int q = 0; q < 8; q++) {
        h += (((a[q] >> 7) & 0xFF) >= 0xC0) + (((b[q] >> 7) & 0xFF) >= 0xC0);
        z += (a[q] == 0) + (b[q] == 0);
    }
    #pragma unroll
    for (int off = 32; off > 0; off >>= 1) {
        h += __shfl_xor(h, off, 64);
        z += __shfl_xor(z, off, 64);
    }
    if ((threadIdx.x & 63) == 0) { atomicAdd(&ch, h); atomicAdd(&cz, z); }
    __syncthreads();
    if (threadIdx.x == 0) *flag = (ch > 250 || cz > 2048) ? 1 : 0;
}

// ---- canonicalize ALL param tensors to bf16 in ONE launch.
#define CANON_TOTAL 445302
__global__ __launch_bounds__(256) void canon_all_kernel(
    const int* __restrict__ flag,
    const void* s0, const void* s1, const void* s2,  const void* s3,
    const void* s4, const void* s5, const void* s6,  const void* s7,
    const void* s8, const void* s9, const void* s10, const void* s11,
    char* __restrict__ ws)
{
    int i = blockIdx.x * 256 + threadIdx.x;
    if (i >= CANON_TOTAL) return;
    const void* srcs[12] = {s0, s1, s2, s3, s4, s5, s6, s7, s8, s9, s10, s11};
    const int cnt[12] = {110592, 36864, 147456, 147456, 192, 192, 192, 192, 192, 768, 192, 1014};
    const int off[12] = {64, 221248, 294976, 589888, 884800, 885184, 885568, 885952, 886336, 886720, 888256, 888640};
    int seg = 0, base = 0;
    while (seg < 11 && i >= base + cnt[seg]) { base += cnt[seg]; seg++; }
    int j = i - base;
    const void* sp = srcs[seg];
    u16* dp = (u16*)(ws + off[seg]);
    dp[j] = (*flag) ? f2b(((const float*)sp)[j]) : ((const u16*)sp)[j];
}

// ---- DMA-stage a 64-row x 192-col bf16 tile into padded LDS [64][200].
__device__ __forceinline__ void stage192(const u16* __restrict__ g, int ldg, u16* s, int tid) {
    #pragma unroll
    for (int it = 0; it < 7; it++) {
        int t = it * 256 + tid;
        if (t < 1600) {                     // 64 rows * 25 chunks
            int row = t / 25, c = t - row * 25;
            int cc = (c == 24) ? 0 : c;
            const u16* src = g + (size_t)row * ldg + cc * 8;
            u16* dst = s + (size_t)(it * 256 + (tid & ~63)) * 8;   // wave base
            __builtin_amdgcn_global_load_lds(
                (const __attribute__((address_space(1))) void*)src,
                (__attribute__((address_space(3))) void*)dst, 16, 0, 0);
        }
    }
}

// ---- in-LDS LayerNorm of the staged 64x192 A tile (rows padded to 200).
__device__ __forceinline__ void ln_lds_rows(u16* As, const u16* __restrict__ w,
                                            const u16* __restrict__ bia, int tid) {
    int r = tid >> 2, p = tid & 3;
    u16* row = As + r * 200 + p * 48;
    u16x8 vv[6];
    float s = 0.f, sq = 0.f;
    #pragma unroll
    for (int j = 0; j < 6; j++) {
        vv[j] = *(const u16x8*)(row + j * 8);
        #pragma unroll
        for (int q = 0; q < 8; q++) { float f = b2f(vv[j][q]); s += f; sq += f * f; }
    }
    s  += __shfl_xor(s, 1, 64);  s  += __shfl_xor(s, 2, 64);
    sq += __shfl_xor(sq, 1, 64); sq += __shfl_xor(sq, 2, 64);
    float mean = s * (1.f / 192.f);
    float var  = fmaxf(sq * (1.f / 192.f) - mean * mean, 0.f);
    float rstd = rsqrtf(var + 1e-5f);
    #pragma unroll
    for (int j = 0; j < 6; j++) {
        u16x8 o;
        #pragma unroll
        for (int q = 0; q < 8; q++) {
            int col = p * 48 + j * 8 + q;
            o[q] = f2b((b2f(vv[j][q]) - mean) * rstd * b2f(w[col]) + b2f(bia[col]));
        }
        *(u16x8*)(row + j * 8) = o;
    }
}

// ---- Fused LN1 A-stage for qkv: gather 64 window-order rows of x via
// map_token (fp32 or bf16 per flag), LayerNorm in registers (4 threads/row,
// shfl_xor(1,2) reduce), write bf16 to As[64][200].
__device__ __forceinline__ void gather_ln(const void* __restrict__ xsrc, int isf,
                                          int mtile, const u16* __restrict__ w,
                                          const u16* __restrict__ bia,
                                          u16* As, int tid) {
    int r = tid >> 2, p = tid & 3;
    int b; int l = map_token(mtile + r, b);
    size_t rowoff = ((size_t)b * LTOK + l) * CCH + p * 48;
    float v[48];
    if (isf) {
        const float* xp = (const float*)xsrc + rowoff;
        #pragma unroll
        for (int j = 0; j < 12; j++) {
            float4 f = *(const float4*)(xp + j * 4);
            v[j * 4 + 0] = f.x; v[j * 4 + 1] = f.y;
            v[j * 4 + 2] = f.z; v[j * 4 + 3] = f.w;
        }
    } else {
        const u16* xp = (const u16*)xsrc + rowoff;
        #pragma unroll
        for (int j = 0; j < 6; j++) {
            u16x8 u = *(const u16x8*)(xp + j * 8);
            #pragma unroll
            for (int q = 0; q < 8; q++) v[j * 8 + q] = b2f(u[q]);
        }
    }
    float s = 0.f, sq = 0.f;
    #pragma unroll
    for (int j = 0; j < 48; j++) { s += v[j]; sq += v[j] * v[j]; }
    s  += __shfl_xor(s, 1, 64);  s  += __shfl_xor(s, 2, 64);
    sq += __shfl_xor(sq, 1, 64); sq += __shfl_xor(sq, 2, 64);
    float mean = s * (1.f / 192.f);
    float var  = fmaxf(sq * (1.f / 192.f) - mean * mean, 0.f);
    float rstd = rsqrtf(var + 1e-5f);
    u16* row = As + r * 200 + p * 48;
    #pragma unroll
    for (int j = 0; j < 6; j++) {
        u16x8 o;
        #pragma unroll
        for (int q = 0; q < 8; q++) {
            int col = p * 48 + j * 8 + q;
            o[q] = f2b((v[j * 8 + q] - mean) * rstd * b2f(w[col]) + b2f(bia[col]));
        }
        *(u16x8*)(row + j * 8) = o;
    }
}

// ---- GEMM K=192 (round-2 verified structure): A tile staged ONCE, NT 64-wide
// n-tiles streamed through a double-buffered B stage. 24 MFMA per barrier.
// MODE 0: qkv with FUSED LN1-gather A-stage (A from Xin via map_token).
// MODE 1: proj + bias + residual scatter into X1.
// MODE 2: fc1 + gelu, LNF=1 applies LayerNorm (LN2) to staged A in LDS.
template<int MODE, int NT, int LNF>
__global__ __launch_bounds__(256) void gemm_k192(
    const u16* __restrict__ A, const u16* __restrict__ Bm, int N,
    const u16* __restrict__ lnw, const u16* __restrict__ lnb,
    const u16* __restrict__ bias,
    u16* __restrict__ Cb, u16* __restrict__ X1, const void* __restrict__ Xin,
    int m_base, const int* __restrict__ flag)
{
    __shared__ __align__(16) u16 As[64 * 200];
    __shared__ __align__(16) u16 Bs[2][64 * 200];
    int isf = *flag;
    int tid = threadIdx.x;
    int m0 = blockIdx.x * 64;
    int wave = tid >> 6, lane = tid & 63;
    int wm = wave >> 1, wn = wave & 1;
    int quad = lane >> 4, mr = lane & 15;

    stage192(Bm, 192, Bs[0], tid);          // B0 DMA overlaps A-stage
    if (MODE == 0) gather_ln(Xin, isf, m_base + m0, lnw, lnb, As, tid);
    else           stage192(A + (size_t)m0 * 192, 192, As, tid);
    __syncthreads();
    if (LNF) { ln_lds_rows(As, lnw, lnb, tid); __syncthreads(); }

    const u16* pa0 = &As[(wm * 32 + mr) * 200 + quad * 8];
    #pragma unroll 1
    for (int nb = 0; nb < NT; nb++) {
        if (nb + 1 < NT)
            stage192(Bm + (size_t)(nb + 1) * 64 * 192, 192, Bs[(nb + 1) & 1], tid);
        const u16* pb0 = &Bs[nb & 1][(wn * 32 + mr) * 200 + quad * 8];
        f32x4 acc00 = {}, acc01 = {}, acc10 = {}, acc11 = {};
        #pragma unroll
        for (int ks = 0; ks < 6; ks++) {
            b16x8 a0 = __builtin_bit_cast(b16x8, *(const u16x8*)(pa0 + ks * 32));
            b16x8 a1 = __builtin_bit_cast(b16x8, *(const u16x8*)(pa0 + 16 * 200 + ks * 32));
            b16x8 b0 = __builtin_bit_cast(b16x8, *(const u16x8*)(pb0 + ks * 32));
            b16x8 b1 = __builtin_bit_cast(b16x8, *(const u16x8*)(pb0 + 16 * 200 + ks * 32));
            acc00 = __builtin_amdgcn_mfma_f32_16x16x32_bf16(a0, b0, acc00, 0, 0, 0);
            acc01 = __builtin_amdgcn_mfma_f32_16x16x32_bf16(a0, b1, acc01, 0, 0, 0);
            acc10 = __builtin_amdgcn_mfma_f32_16x16x32_bf16(a1, b0, acc10, 0, 0, 0);
            acc11 = __builtin_amdgcn_mfma_f32_16x16x32_bf16(a1, b1, acc11, 0, 0, 0);
        }
        int n0 = nb * 64;
        f32x4 accs[2][2] = {{acc00, acc01}, {acc10, acc11}};
        #pragma unroll
        for (int sm = 0; sm < 2; sm++) {
            #pragma unroll
            for (int sn = 0; sn < 2; sn++) {
                f32x4 v = accs[sm][sn];
                int nn = n0 + wn * 32 + sn * 16 + mr;
                int mb = m0 + wm * 32 + sm * 16 + quad * 4;
                #pragma unroll
                for (int r = 0; r < 4; r++) {
                    int mm = mb + r;
                    float val = v[r];
                    if (MODE == 0) {
                        Cb[(size_t)mm * N + nn] = f2b(val);
                    } else if (MODE == 1) {
                        val += b2f(bias[nn]);
                        int b; int l = map_token(m_base + mm, b);
                        size_t idx = ((size_t)b * LTOK + l) * CCH + nn;
                        float xi = isf ? ((const float*)Xin)[idx] : b2f(((const u16*)Xin)[idx]);
                        X1[idx] = f2b(xi + val);
                    } else {
                        val = gelu_exact(val + b2f(bias[nn]));
                        Cb[(size_t)mm * N + nn] = f2b(val);
                    }
                }
            }
        }
        __syncthreads();   // B(nb+1) DMA drained; Bs[nb&1] free for re-stage
    }
}

// ---- DMA-stage a ROWSx32 bf16 chunk (row stride ldk u16) into LINEAR LDS
// [ROWS][32] with chunk swizzle (lds chunk c holds global chunk c^((row>>1)&3);
// pre-swizzled global source, same XOR on read). Uniform ROWS*4/256 loads/thread.
template<int ROWS>
__device__ __forceinline__ void stageL(const u16* __restrict__ g, int ldk, u16* s, int tid) {
    constexpr int ITER = ROWS * 4 / 256;
    #pragma unroll
    for (int it = 0; it < ITER; it++) {
        int t = it * 256 + tid;
        int row = t >> 2, c = t & 3;
        int cc = c ^ ((row >> 1) & 3);
        const u16* src = g + (size_t)row * ldk + cc * 8;
        u16* dst = s + (size_t)(it * 256 + (tid & ~63)) * 8;   // wave base
        __builtin_amdgcn_global_load_lds(
            (const __attribute__((address_space(1))) void*)src,
            (__attribute__((address_space(3))) void*)dst, 16, 0, 0);
    }
}

// ---- fc2 GEMM (round-7 verified, 127us / 0 conflicts): 128M x 192N, BK=32,
// 2 LDS buffers (40.6KB -> 3 blocks/CU), counted vmcnt(5) pipeline.
// MODE 3 epilogue: gelu + bias + residual(X1) -> Oout (dtype per flag).
template<int KK>
__global__ __launch_bounds__(256, 3) void gemm_t3(
    const u16* __restrict__ A, const u16* __restrict__ Bm,
    const u16* __restrict__ bias,
    const u16* __restrict__ X1,
    void* __restrict__ Oout, size_t o_off,
    const int* __restrict__ flag)
{
    __shared__ __align__(16) u16 As[2][128 * 32];
    __shared__ __align__(16) u16 Bs[2][192 * 32];
    int tid = threadIdx.x;
    int m0 = blockIdx.x * 128, n0 = blockIdx.y * 192;
    int wave = tid >> 6, lane = tid & 63;
    int wm = wave >> 1, wn = wave & 1;
    int quad = lane >> 4, mr = lane & 15;

    const u16* Ag = A + (size_t)m0 * KK;
    const u16* Bg = Bm + (size_t)n0 * KK;

    stageL<128>(Ag, KK, As[0], tid);
    stageL<192>(Bg, KK, Bs[0], tid);

    f32x4 acc[4][6] = {};
    constexpr int NSTEP = KK / 32;

    #pragma unroll 1
    for (int t = 0; t < NSTEP; t++) {
        int cur = t & 1;
        if (t + 1 < NSTEP) {
            stageL<128>(Ag + (t + 1) * 32, KK, As[cur ^ 1], tid);
            stageL<192>(Bg + (t + 1) * 32, KK, Bs[cur ^ 1], tid);
            asm volatile("s_waitcnt vmcnt(5)");   // stage(t) landed; 5 in flight
        } else {
            asm volatile("s_waitcnt vmcnt(0)");   // last step: full drain
        }
        __builtin_amdgcn_s_barrier();
        __builtin_amdgcn_sched_barrier(0);
        b16x8 a[4], b[6];
        #pragma unroll
        for (int sm = 0; sm < 4; sm++) {
            int row = wm * 64 + sm * 16 + mr;
            a[sm] = __builtin_bit_cast(b16x8,
                *(const u16x8*)&As[cur][row * 32 + (quad ^ ((row >> 1) & 3)) * 8]);
        }
        #pragma unroll
        for (int sn = 0; sn < 6; sn++) {
            int row = wn * 96 + sn * 16 + mr;
            b[sn] = __builtin_bit_cast(b16x8,
                *(const u16x8*)&Bs[cur][row * 32 + (quad ^ ((row >> 1) & 3)) * 8]);
        }
        #pragma unroll
        for (int sm = 0; sm < 4; sm++)
            #pragma unroll
            for (int sn = 0; sn < 6; sn++)
                acc[sm][sn] = __builtin_amdgcn_mfma_f32_16x16x32_bf16(a[sm], b[sn], acc[sm][sn], 0, 0, 0);
        __builtin_amdgcn_sched_barrier(0);
        __builtin_amdgcn_s_barrier();             // protect buf before re-stage
    }

    int isf = *flag;
    #pragma unroll
    for (int sm = 0; sm < 4; sm++) {
        #pragma unroll
        for (int r = 0; r < 4; r++) {
            int mm = m0 + wm * 64 + sm * 16 + quad * 4 + r;
            #pragma unroll
            for (int sn = 0; sn < 6; sn++) {
                int nn = n0 + wn * 96 + sn * 16 + mr;
                float val = gelu_exact(acc[sm][sn][r] + b2f(bias[nn]));
                size_t idx = (size_t)mm * CCH + nn;
                float r2 = val + b2f(X1[idx]);
                if (isf) ((float*)Oout)[o_off + idx] = r2;
                else     ((u16*)Oout)[o_off + idx]  = f2b(r2);
            }
        }
    }
}

// ---- MFMA attention (unchanged, verified)
__global__ __launch_bounds__(256) void attn_kernel(
    const u16* __restrict__ qkv, const u16* __restrict__ rel_bias,
    u16* __restrict__ aout)
{
    __shared__ __align__(16) u16 qs[64 * 32];
    __shared__ __align__(16) u16 ks[64 * 32];
    __shared__ __align__(16) u16 vsT[32 * 72];
    __shared__ __align__(16) u16 ps[64 * 72];
    __shared__ float bias_s[169];
    int blk = blockIdx.x;
    int widx = blk / NHEAD, head = blk - widx * NHEAD;
    int wloc = widx & 63;
    int wh = wloc >> 3, ww = wloc & 7;
    int tid = threadIdx.x;
    const u16* base = qkv + (size_t)widx * LW * 576 + head * HDIM;

    if (tid < 196) {
        int i = tid >> 2, c8 = (tid & 3) * 8;
        *(uint4*)&qs[i * 32 + c8] = *(const uint4*)(base + (size_t)i * 576 + c8);
        *(uint4*)&ks[i * 32 + c8] = *(const uint4*)(base + (size_t)i * 576 + 192 + c8);
        u16x8 vv = *(const u16x8*)(base + (size_t)i * 576 + 384 + c8);
        #pragma unroll
        for (int q = 0; q < 8; q++) vsT[(c8 + q) * 72 + i] = vv[q];
    }
    for (int idx = tid; idx < 32 * 15; idx += 256) {   // zero pad cols 49..63
        int d = idx / 15, j = 49 + (idx - d * 15);
        vsT[d * 72 + j] = 0;
    }
    if (tid < 169) bias_s[tid] = b2f(rel_bias[tid * NHEAD + head]);
    __syncthreads();

    int wave = tid >> 6, lane = tid & 63;
    int quad = lane >> 4, c = lane & 15;

    b16x8 aq = __builtin_bit_cast(b16x8, *(const u16x8*)&qs[(wave * 16 + c) * 32 + quad * 8]);
    f32x4 sacc[4];
    #pragma unroll
    for (int nt = 0; nt < 4; nt++) {
        b16x8 bk = __builtin_bit_cast(b16x8, *(const u16x8*)&ks[(nt * 16 + c) * 32 + quad * 8]);
        f32x4 z = {};
        sacc[nt] = __builtin_amdgcn_mfma_f32_16x16x32_bf16(aq, bk, z, 0, 0, 0);
    }

    const float SCALE = 13.856406460551018f;
    float val[4][4];
    int rbase = wave * 16 + quad * 4;
    #pragma unroll
    for (int r = 0; r < 4; r++) {
        int i = rbase + r;
        int ih = i / WS7, iw = i - ih * WS7;
        int ri = (wh == 7 ? (ih < 4 ? 1 : 2) : 0) * 3 + (ww == 7 ? (iw < 4 ? 1 : 2) : 0);
        #pragma unroll
        for (int nt = 0; nt < 4; nt++) {
            int j = nt * 16 + c;
            float v;
            if (i >= LW) v = 0.f;
            else if (j >= LW) v = -1e30f;
            else {
                int jh = j / WS7, jw = j - jh * WS7;
                int rj = (wh == 7 ? (jh < 4 ? 1 : 2) : 0) * 3 + (ww == 7 ? (jw < 4 ? 1 : 2) : 0);
                if (ri != rj) v = -100.0f;
                else v = fmaf(sacc[nt][r], SCALE, bias_s[(ih - jh + 6) * 13 + (iw - jw + 6)]);
            }
            val[r][nt] = v;
        }
    }

    #pragma unroll
    for (int r = 0; r < 4; r++) {
        float mx = fmaxf(fmaxf(val[r][0], val[r][1]), fmaxf(val[r][2], val[r][3]));
        for (int d = 1; d < 16; d <<= 1) mx = fmaxf(mx, __shfl_xor(mx, d, 64));
        float sum = 0.f;
        #pragma unroll
        for (int nt = 0; nt < 4; nt++) { float e = expf(val[r][nt] - mx); val[r][nt] = e; sum += e; }
        for (int d = 1; d < 16; d <<= 1) sum += __shfl_xor(sum, d, 64);
        float inv = 1.f / sum;
        int i = rbase + r;
        #pragma unroll
        for (int nt = 0; nt < 4; nt++)
            ps[i * 72 + nt * 16 + c] = f2b(val[r][nt] * inv);
    }

    f32x4 oacc[2] = {{}, {}};
    #pragma unroll
    for (int kh = 0; kh < 2; kh++) {
        b16x8 ap = __builtin_bit_cast(b16x8, *(const u16x8*)&ps[(wave * 16 + c) * 72 + kh * 32 + quad * 8]);
        #pragma unroll
        for (int nt = 0; nt < 2; nt++) {
            b16x8 bv = __builtin_bit_cast(b16x8, *(const u16x8*)&vsT[(nt * 16 + c) * 72 + kh * 32 + quad * 8]);
            oacc[nt] = __builtin_amdgcn_mfma_f32_16x16x32_bf16(ap, bv, oacc[nt], 0, 0, 0);
        }
    }
    #pragma unroll
    for (int nt = 0; nt < 2; nt++) {
        #pragma unroll
        for (int r = 0; r < 4; r++) {
            int i = rbase + r;
            if (i < LW)
                aout[((size_t)widx * LW + i) * CCH + head * HDIM + nt * 16 + c] = f2b(oacc[nt][r]);
        }
    }
}

extern "C" void kernel_launch(void* const* d_in, const int* in_sizes, int n_in,
                              void* d_out, int out_size, void* d_ws, size_t ws_size,
                              hipStream_t stream)
{
    const void* x_in = d_in[0];
    char* ws = (char*)d_ws;
    int* flag = (int*)ws;

    u16* qkvw_c  = (u16*)(ws + 64);
    u16* projw_c = (u16*)(ws + 221248);
    u16* fc1w_c  = (u16*)(ws + 294976);
    u16* fc2w_c  = (u16*)(ws + 589888);
    u16* n1w_c   = (u16*)(ws + 884800);
    u16* n1b_c   = (u16*)(ws + 885184);
    u16* n2w_c   = (u16*)(ws + 885568);
    u16* n2b_c   = (u16*)(ws + 885952);
    u16* projb_c = (u16*)(ws + 886336);
    u16* fc1b_c  = (u16*)(ws + 886720);
    u16* fc2b_c  = (u16*)(ws + 888256);
    u16* relb_c  = (u16*)(ws + 888640);

    const size_t P0 = 1u << 20;
    const size_t X1SZ   = (size_t)MTOK * CCH * 2;   //  38,535,168
    const size_t QKVSZ  = (size_t)MTOK * 576 * 2;   // 115,605,504
    const size_t H1FULL = (size_t)MTOK * 768 * 2;   // 154,140,672

    u16* x1 = (u16*)(ws + P0);

    probe_kernel<<<1, 1024, 0, stream>>>((const u16*)x_in, flag);
    canon_all_kernel<<<(CANON_TOTAL + 255) / 256, 256, 0, stream>>>(
        flag,
        d_in[7], d_in[9], d_in[13], d_in[15],
        d_in[5], d_in[6], d_in[11], d_in[12],
        d_in[10], d_in[14], d_in[16], d_in[8],
        ws);

    // ---- workspace tiering (round-10 verified layout).
    int QC, EC;
    u16 *aoutb, *qkvq, *h1q;
    if (ws_size >= P0 + 2 * X1SZ + H1FULL) {            // 232.3 MB
        QC = 1; EC = 1;
        aoutb = (u16*)(ws + P0 + X1SZ);
        qkvq  = (u16*)(ws + P0 + 2 * X1SZ);
        h1q   = qkvq;                                   // qkvq dead in MLP phase
    } else if (ws_size >= P0 + 2 * X1SZ + QKVSZ) {      // 193.7 MB
        QC = 1; EC = 2;
        aoutb = (u16*)(ws + P0 + X1SZ);
        qkvq  = (u16*)(ws + P0 + 2 * X1SZ);
        h1q   = qkvq;                                   // half-h1 (77MB) fits
    } else {                                            // proven 78.1 MB layout
        QC = 4; EC = 8;
        aoutb = (u16*)(ws + P0 + X1SZ);
        qkvq  = (u16*)(ws + P0 + X1SZ + 9633792);
        h1q   = (u16*)(ws + P0 + X1SZ);
    }

    const int MQ = MTOK / QC;
    const int ME = MTOK / EC;

    for (int q = 0; q < QC; q++) {
        int mb = q * MQ;
        gemm_k192<0, 9, 0><<<MQ / 64, 256, 0, stream>>>(
            nullptr, qkvw_c, 576, n1w_c, n1b_c, nullptr, qkvq, nullptr, x_in, mb, flag);
        attn_kernel<<<(NWTOT / QC) * NHEAD, 256, 0, stream>>>(qkvq, relb_c, aoutb);
        gemm_k192<1, 3, 0><<<MQ / 64, 256, 0, stream>>>(
            aoutb, projw_c, 192, nullptr, nullptr, projb_c, nullptr, x1, x_in, mb, flag);
    }

    for (int e = 0; e < EC; e++) {
        size_t off = (size_t)e * ME * CCH;
        gemm_k192<2, 12, 1><<<ME / 64, 256, 0, stream>>>(
            x1 + off, fc1w_c, 768, n2w_c, n2b_c, fc1b_c, h1q, nullptr, nullptr, 0, flag);
        gemm_t3<768><<<dim3(ME / 128, 1), 256, 0, stream>>>(
            h1q, fc2w_c, fc2b_c, x1 + off, d_out, off, flag);
    }
}

// Round 12
// 571.312 us; speedup vs baseline: 1.0287x; 1.0287x over previous
//
#include <hip/hip_runtime.h>

#define WS7    7
#define SHIFT3 3
#define NHEAD  6
#define CCH    192
#define HDIM   32
#define HH56   56
#define LTOK   (HH56*HH56)      // 3136
#define NWIN   64
#define NBATCH 32
#define NWTOT  (NBATCH*NWIN)    // 2048
#define LW     49
#define MTOK   (NWTOT*LW)       // 100352

typedef unsigned short u16;
typedef unsigned int   u32;
typedef __bf16 b16;
typedef b16   b16x8 __attribute__((ext_vector_type(8)));
typedef u16   u16x8 __attribute__((ext_vector_type(8)));
typedef float f32x4 __attribute__((ext_vector_type(4)));

__device__ __forceinline__ float b2f(u16 u) {
    u32 x = ((u32)u) << 16;
    return __builtin_bit_cast(float, x);
}
__device__ __forceinline__ u16 f2b(float f) {
    u32 x = __builtin_bit_cast(u32, f);
    u32 r = x + 0x7FFFu + ((x >> 16) & 1u);
    return (u16)(r >> 16);
}
// Fast exact-accuracy gelu: erf via Abramowitz-Stegun 7.1.26 (|err|<1.5e-7,
// below bf16 quantum -> numerically equivalent to erff for our outputs).
// Branchless, ~16 VALU ops vs libm erff's ~25-30.
__device__ __forceinline__ float gelu_exact(float x) {
    float z  = x * 0.7071067811865475f;
    float az = fabsf(z);
    float t  = __fdividef(1.0f, fmaf(0.3275911f, az, 1.0f));
    float p  = t * fmaf(t, fmaf(t, fmaf(t, fmaf(t, 1.061405429f, -1.453152027f),
                        1.421413741f), -0.284496736f), 0.254829592f);
    float e  = __expf(-az * az);
    float erfv = copysignf(fmaf(-p, e, 1.0f), z);
    return 0.5f * x * (1.0f + erfv);
}

// token m (window-order) -> (b, l) image order (bijection)
__device__ __forceinline__ int map_token(int m, int &b) {
    int widx = m / LW, p = m - widx * LW;
    b = widx >> 6;
    int wloc = widx & 63;
    int wh = wloc >> 3, ww = wloc & 7;
    int i = p / WS7, j = p - i * WS7;
    int gh = wh * WS7 + i + SHIFT3; if (gh >= HH56) gh -= HH56;
    int gw = ww * WS7 + j + SHIFT3; if (gw >= HH56) gw -= HH56;
    return gh * HH56 + gw;
}

// ---- dtype probe: flag=1 if x is fp32 storage, 0 if bf16 storage.
__global__ __launch_bounds__(1024) void probe_kernel(const u16* __restrict__ x, int* flag) {
    __shared__ int ch, cz;
    if (threadIdx.x == 0) { ch = 0; cz = 0; }
    __syncthreads();
    int i = threadIdx.x * 16;
    u16x8 a = *(const u16x8*)(x + i);
    u16x8 b = *(const u16x8*)(x + i + 8);
    int h = 0, z = 0;
    #pragma unroll
    for (int q = 0; q < 8; q++) {
        h += (((a[q] >> 7) & 0xFF) >= 0xC0) + (((b[q] >> 7) & 0xFF) >= 0xC0);
        z += (a[q] == 0) + (b[q] == 0);
    }
    #pragma unroll
    for (int off = 32; off > 0; off >>= 1) {
        h += __shfl_xor(h, off, 64);
        z += __shfl_xor(z, off, 64);
    }
    if ((threadIdx.x & 63) == 0) { atomicAdd(&ch, h); atomicAdd(&cz, z); }
    __syncthreads();
    if (threadIdx.x == 0) *flag = (ch > 250 || cz > 2048) ? 1 : 0;
}

// ---- canonicalize ALL param tensors to bf16 in ONE launch.
#define CANON_TOTAL 445302
__global__ __launch_bounds__(256) void canon_all_kernel(
    const int* __restrict__ flag,
    const void* s0, const void* s1, const void* s2,  const void* s3,
    const void* s4, const void* s5, const void* s6,  const void* s7,
    const void* s8, const void* s9, const void* s10, const void* s11,
    char* __restrict__ ws)
{
    int i = blockIdx.x * 256 + threadIdx.x;
    if (i >= CANON_TOTAL) return;
    const void* srcs[12] = {s0, s1, s2, s3, s4, s5, s6, s7, s8, s9, s10, s11};
    const int cnt[12] = {110592, 36864, 147456, 147456, 192, 192, 192, 192, 192, 768, 192, 1014};
    const int off[12] = {64, 221248, 294976, 589888, 884800, 885184, 885568, 885952, 886336, 886720, 888256, 888640};
    int seg = 0, base = 0;
    while (seg < 11 && i >= base + cnt[seg]) { base += cnt[seg]; seg++; }
    int j = i - base;
    const void* sp = srcs[seg];
    u16* dp = (u16*)(ws + off[seg]);
    dp[j] = (*flag) ? f2b(((const float*)sp)[j]) : ((const u16*)sp)[j];
}

// ---- DMA-stage a 64-row x 192-col bf16 tile into padded LDS [64][200].
__device__ __forceinline__ void stage192(const u16* __restrict__ g, int ldg, u16* s, int tid) {
    #pragma unroll
    for (int it = 0; it < 7; it++) {
        int t = it * 256 + tid;
        if (t < 1600) {                     // 64 rows * 25 chunks
            int row = t / 25, c = t - row * 25;
            int cc = (c == 24) ? 0 : c;
            const u16* src = g + (size_t)row * ldg + cc * 8;
            u16* dst = s + (size_t)(it * 256 + (tid & ~63)) * 8;   // wave base
            __builtin_amdgcn_global_load_lds(
                (const __attribute__((address_space(1))) void*)src,
                (__attribute__((address_space(3))) void*)dst, 16, 0, 0);
        }
    }
}

// ---- in-LDS LayerNorm of the staged 64x192 A tile (rows padded to 200).
__device__ __forceinline__ void ln_lds_rows(u16* As, const u16* __restrict__ w,
                                            const u16* __restrict__ bia, int tid) {
    int r = tid >> 2, p = tid & 3;
    u16* row = As + r * 200 + p * 48;
    u16x8 vv[6];
    float s = 0.f, sq = 0.f;
    #pragma unroll
    for (int j = 0; j < 6; j++) {
        vv[j] = *(const u16x8*)(row + j * 8);
        #pragma unroll
        for (int q = 0; q < 8; q++) { float f = b2f(vv[j][q]); s += f; sq += f * f; }
    }
    s  += __shfl_xor(s, 1, 64);  s  += __shfl_xor(s, 2, 64);
    sq += __shfl_xor(sq, 1, 64); sq += __shfl_xor(sq, 2, 64);
    float mean = s * (1.f / 192.f);
    float var  = fmaxf(sq * (1.f / 192.f) - mean * mean, 0.f);
    float rstd = rsqrtf(var + 1e-5f);
    #pragma unroll
    for (int j = 0; j < 6; j++) {
        u16x8 o;
        #pragma unroll
        for (int q = 0; q < 8; q++) {
            int col = p * 48 + j * 8 + q;
            o[q] = f2b((b2f(vv[j][q]) - mean) * rstd * b2f(w[col]) + b2f(bia[col]));
        }
        *(u16x8*)(row + j * 8) = o;
    }
}

// ---- Fused LN1 A-stage for qkv: gather 64 window-order rows of x via
// map_token (fp32 or bf16 per flag), LayerNorm in registers (4 threads/row,
// shfl_xor(1,2) reduce), write bf16 to As[64][200].
__device__ __forceinline__ void gather_ln(const void* __restrict__ xsrc, int isf,
                                          int mtile, const u16* __restrict__ w,
                                          const u16* __restrict__ bia,
                                          u16* As, int tid) {
    int r = tid >> 2, p = tid & 3;
    int b; int l = map_token(mtile + r, b);
    size_t rowoff = ((size_t)b * LTOK + l) * CCH + p * 48;
    float v[48];
    if (isf) {
        const float* xp = (const float*)xsrc + rowoff;
        #pragma unroll
        for (int j = 0; j < 12; j++) {
            float4 f = *(const float4*)(xp + j * 4);
            v[j * 4 + 0] = f.x; v[j * 4 + 1] = f.y;
            v[j * 4 + 2] = f.z; v[j * 4 + 3] = f.w;
        }
    } else {
        const u16* xp = (const u16*)xsrc + rowoff;
        #pragma unroll
        for (int j = 0; j < 6; j++) {
            u16x8 u = *(const u16x8*)(xp + j * 8);
            #pragma unroll
            for (int q = 0; q < 8; q++) v[j * 8 + q] = b2f(u[q]);
        }
    }
    float s = 0.f, sq = 0.f;
    #pragma unroll
    for (int j = 0; j < 48; j++) { s += v[j]; sq += v[j] * v[j]; }
    s  += __shfl_xor(s, 1, 64);  s  += __shfl_xor(s, 2, 64);
    sq += __shfl_xor(sq, 1, 64); sq += __shfl_xor(sq, 2, 64);
    float mean = s * (1.f / 192.f);
    float var  = fmaxf(sq * (1.f / 192.f) - mean * mean, 0.f);
    float rstd = rsqrtf(var + 1e-5f);
    u16* row = As + r * 200 + p * 48;
    #pragma unroll
    for (int j = 0; j < 6; j++) {
        u16x8 o;
        #pragma unroll
        for (int q = 0; q < 8; q++) {
            int col = p * 48 + j * 8 + q;
            o[q] = f2b((v[j * 8 + q] - mean) * rstd * b2f(w[col]) + b2f(bia[col]));
        }
        *(u16x8*)(row + j * 8) = o;
    }
}

// ---- GEMM K=192 (round-2 verified structure): A tile staged ONCE, NT 64-wide
// n-tiles streamed through a double-buffered B stage. 24 MFMA per barrier.
// MODE 0: qkv with FUSED LN1-gather A-stage (A from Xin via map_token).
// MODE 1: proj + bias + residual scatter into X1.
// MODE 2: fc1 + gelu, LNF=1 applies LayerNorm (LN2) to staged A in LDS.
template<int MODE, int NT, int LNF>
__global__ __launch_bounds__(256) void gemm_k192(
    const u16* __restrict__ A, const u16* __restrict__ Bm, int N,
    const u16* __restrict__ lnw, const u16* __restrict__ lnb,
    const u16* __restrict__ bias,
    u16* __restrict__ Cb, u16* __restrict__ X1, const void* __restrict__ Xin,
    int m_base, const int* __restrict__ flag)
{
    __shared__ __align__(16) u16 As[64 * 200];
    __shared__ __align__(16) u16 Bs[2][64 * 200];
    int isf = *flag;
    int tid = threadIdx.x;
    int m0 = blockIdx.x * 64;
    int wave = tid >> 6, lane = tid & 63;
    int wm = wave >> 1, wn = wave & 1;
    int quad = lane >> 4, mr = lane & 15;

    stage192(Bm, 192, Bs[0], tid);          // B0 DMA overlaps A-stage
    if (MODE == 0) gather_ln(Xin, isf, m_base + m0, lnw, lnb, As, tid);
    else           stage192(A + (size_t)m0 * 192, 192, As, tid);
    __syncthreads();
    if (LNF) { ln_lds_rows(As, lnw, lnb, tid); __syncthreads(); }

    const u16* pa0 = &As[(wm * 32 + mr) * 200 + quad * 8];
    #pragma unroll 1
    for (int nb = 0; nb < NT; nb++) {
        if (nb + 1 < NT)
            stage192(Bm + (size_t)(nb + 1) * 64 * 192, 192, Bs[(nb + 1) & 1], tid);
        const u16* pb0 = &Bs[nb & 1][(wn * 32 + mr) * 200 + quad * 8];
        f32x4 acc00 = {}, acc01 = {}, acc10 = {}, acc11 = {};
        #pragma unroll
        for (int ks = 0; ks < 6; ks++) {
            b16x8 a0 = __builtin_bit_cast(b16x8, *(const u16x8*)(pa0 + ks * 32));
            b16x8 a1 = __builtin_bit_cast(b16x8, *(const u16x8*)(pa0 + 16 * 200 + ks * 32));
            b16x8 b0 = __builtin_bit_cast(b16x8, *(const u16x8*)(pb0 + ks * 32));
            b16x8 b1 = __builtin_bit_cast(b16x8, *(const u16x8*)(pb0 + 16 * 200 + ks * 32));
            acc00 = __builtin_amdgcn_mfma_f32_16x16x32_bf16(a0, b0, acc00, 0, 0, 0);
            acc01 = __builtin_amdgcn_mfma_f32_16x16x32_bf16(a0, b1, acc01, 0, 0, 0);
            acc10 = __builtin_amdgcn_mfma_f32_16x16x32_bf16(a1, b0, acc10, 0, 0, 0);
            acc11 = __builtin_amdgcn_mfma_f32_16x16x32_bf16(a1, b1, acc11, 0, 0, 0);
        }
        int n0 = nb * 64;
        f32x4 accs[2][2] = {{acc00, acc01}, {acc10, acc11}};
        #pragma unroll
        for (int sm = 0; sm < 2; sm++) {
            #pragma unroll
            for (int sn = 0; sn < 2; sn++) {
                f32x4 v = accs[sm][sn];
                int nn = n0 + wn * 32 + sn * 16 + mr;
                int mb = m0 + wm * 32 + sm * 16 + quad * 4;
                #pragma unroll
                for (int r = 0; r < 4; r++) {
                    int mm = mb + r;
                    float val = v[r];
                    if (MODE == 0) {
                        Cb[(size_t)mm * N + nn] = f2b(val);
                    } else if (MODE == 1) {
                        val += b2f(bias[nn]);
                        int b; int l = map_token(m_base + mm, b);
                        size_t idx = ((size_t)b * LTOK + l) * CCH + nn;
                        float xi = isf ? ((const float*)Xin)[idx] : b2f(((const u16*)Xin)[idx]);
                        X1[idx] = f2b(xi + val);
                    } else {
                        val = gelu_exact(val + b2f(bias[nn]));
                        Cb[(size_t)mm * N + nn] = f2b(val);
                    }
                }
            }
        }
        __syncthreads();   // B(nb+1) DMA drained; Bs[nb&1] free for re-stage
    }
}

// ---- DMA-stage a ROWSx32 bf16 chunk (row stride ldk u16) into LINEAR LDS
// [ROWS][32] with chunk swizzle (lds chunk c holds global chunk c^((row>>1)&3);
// pre-swizzled global source, same XOR on read). Uniform ROWS*4/256 loads/thread.
template<int ROWS>
__device__ __forceinline__ void stageL(const u16* __restrict__ g, int ldk, u16* s, int tid) {
    constexpr int ITER = ROWS * 4 / 256;
    #pragma unroll
    for (int it = 0; it < ITER; it++) {
        int t = it * 256 + tid;
        int row = t >> 2, c = t & 3;
        int cc = c ^ ((row >> 1) & 3);
        const u16* src = g + (size_t)row * ldk + cc * 8;
        u16* dst = s + (size_t)(it * 256 + (tid & ~63)) * 8;   // wave base
        __builtin_amdgcn_global_load_lds(
            (const __attribute__((address_space(1))) void*)src,
            (__attribute__((address_space(3))) void*)dst, 16, 0, 0);
    }
}

// ---- fc2 GEMM (round-7 verified, 127us / 0 conflicts): 128M x 192N, BK=32,
// 2 LDS buffers (40.6KB -> 3 blocks/CU), counted vmcnt(5) pipeline.
// Epilogue: gelu + bias + residual(X1) -> Oout (dtype per flag).
template<int KK>
__global__ __launch_bounds__(256, 3) void gemm_t3(
    const u16* __restrict__ A, const u16* __restrict__ Bm,
    const u16* __restrict__ bias,
    const u16* __restrict__ X1,
    void* __restrict__ Oout, size_t o_off,
    const int* __restrict__ flag)
{
    __shared__ __align__(16) u16 As[2][128 * 32];
    __shared__ __align__(16) u16 Bs[2][192 * 32];
    int tid = threadIdx.x;
    int m0 = blockIdx.x * 128, n0 = blockIdx.y * 192;
    int wave = tid >> 6, lane = tid & 63;
    int wm = wave >> 1, wn = wave & 1;
    int quad = lane >> 4, mr = lane & 15;

    const u16* Ag = A + (size_t)m0 * KK;
    const u16* Bg = Bm + (size_t)n0 * KK;

    stageL<128>(Ag, KK, As[0], tid);
    stageL<192>(Bg, KK, Bs[0], tid);

    f32x4 acc[4][6] = {};
    constexpr int NSTEP = KK / 32;

    #pragma unroll 1
    for (int t = 0; t < NSTEP; t++) {
        int cur = t & 1;
        if (t + 1 < NSTEP) {
            stageL<128>(Ag + (t + 1) * 32, KK, As[cur ^ 1], tid);
            stageL<192>(Bg + (t + 1) * 32, KK, Bs[cur ^ 1], tid);
            asm volatile("s_waitcnt vmcnt(5)");   // stage(t) landed; 5 in flight
        } else {
            asm volatile("s_waitcnt vmcnt(0)");   // last step: full drain
        }
        __builtin_amdgcn_s_barrier();
        __builtin_amdgcn_sched_barrier(0);
        b16x8 a[4], b[6];
        #pragma unroll
        for (int sm = 0; sm < 4; sm++) {
            int row = wm * 64 + sm * 16 + mr;
            a[sm] = __builtin_bit_cast(b16x8,
                *(const u16x8*)&As[cur][row * 32 + (quad ^ ((row >> 1) & 3)) * 8]);
        }
        #pragma unroll
        for (int sn = 0; sn < 6; sn++) {
            int row = wn * 96 + sn * 16 + mr;
            b[sn] = __builtin_bit_cast(b16x8,
                *(const u16x8*)&Bs[cur][row * 32 + (quad ^ ((row >> 1) & 3)) * 8]);
        }
        #pragma unroll
        for (int sm = 0; sm < 4; sm++)
            #pragma unroll
            for (int sn = 0; sn < 6; sn++)
                acc[sm][sn] = __builtin_amdgcn_mfma_f32_16x16x32_bf16(a[sm], b[sn], acc[sm][sn], 0, 0, 0);
        __builtin_amdgcn_sched_barrier(0);
        __builtin_amdgcn_s_barrier();             // protect buf before re-stage
    }

    int isf = *flag;
    #pragma unroll
    for (int sm = 0; sm < 4; sm++) {
        #pragma unroll
        for (int r = 0; r < 4; r++) {
            int mm = m0 + wm * 64 + sm * 16 + quad * 4 + r;
            #pragma unroll
            for (int sn = 0; sn < 6; sn++) {
                int nn = n0 + wn * 96 + sn * 16 + mr;
                float val = gelu_exact(acc[sm][sn][r] + b2f(bias[nn]));
                size_t idx = (size_t)mm * CCH + nn;
                float r2 = val + b2f(X1[idx]);
                if (isf) ((float*)Oout)[o_off + idx] = r2;
                else     ((u16*)Oout)[o_off + idx]  = f2b(r2);
            }
        }
    }
}

// ---- MFMA attention (unchanged, verified)
__global__ __launch_bounds__(256) void attn_kernel(
    const u16* __restrict__ qkv, const u16* __restrict__ rel_bias,
    u16* __restrict__ aout)
{
    __shared__ __align__(16) u16 qs[64 * 32];
    __shared__ __align__(16) u16 ks[64 * 32];
    __shared__ __align__(16) u16 vsT[32 * 72];
    __shared__ __align__(16) u16 ps[64 * 72];
    __shared__ float bias_s[169];
    int blk = blockIdx.x;
    int widx = blk / NHEAD, head = blk - widx * NHEAD;
    int wloc = widx & 63;
    int wh = wloc >> 3, ww = wloc & 7;
    int tid = threadIdx.x;
    const u16* base = qkv + (size_t)widx * LW * 576 + head * HDIM;

    if (tid < 196) {
        int i = tid >> 2, c8 = (tid & 3) * 8;
        *(uint4*)&qs[i * 32 + c8] = *(const uint4*)(base + (size_t)i * 576 + c8);
        *(uint4*)&ks[i * 32 + c8] = *(const uint4*)(base + (size_t)i * 576 + 192 + c8);
        u16x8 vv = *(const u16x8*)(base + (size_t)i * 576 + 384 + c8);
        #pragma unroll
        for (int q = 0; q < 8; q++) vsT[(c8 + q) * 72 + i] = vv[q];
    }
    for (int idx = tid; idx < 32 * 15; idx += 256) {   // zero pad cols 49..63
        int d = idx / 15, j = 49 + (idx - d * 15);
        vsT[d * 72 + j] = 0;
    }
    if (tid < 169) bias_s[tid] = b2f(rel_bias[tid * NHEAD + head]);
    __syncthreads();

    int wave = tid >> 6, lane = tid & 63;
    int quad = lane >> 4, c = lane & 15;

    b16x8 aq = __builtin_bit_cast(b16x8, *(const u16x8*)&qs[(wave * 16 + c) * 32 + quad * 8]);
    f32x4 sacc[4];
    #pragma unroll
    for (int nt = 0; nt < 4; nt++) {
        b16x8 bk = __builtin_bit_cast(b16x8, *(const u16x8*)&ks[(nt * 16 + c) * 32 + quad * 8]);
        f32x4 z = {};
        sacc[nt] = __builtin_amdgcn_mfma_f32_16x16x32_bf16(aq, bk, z, 0, 0, 0);
    }

    const float SCALE = 13.856406460551018f;
    float val[4][4];
    int rbase = wave * 16 + quad * 4;
    #pragma unroll
    for (int r = 0; r < 4; r++) {
        int i = rbase + r;
        int ih = i / WS7, iw = i - ih * WS7;
        int ri = (wh == 7 ? (ih < 4 ? 1 : 2) : 0) * 3 + (ww == 7 ? (iw < 4 ? 1 : 2) : 0);
        #pragma unroll
        for (int nt = 0; nt < 4; nt++) {
            int j = nt * 16 + c;
            float v;
            if (i >= LW) v = 0.f;
            else if (j >= LW) v = -1e30f;
            else {
                int jh = j / WS7, jw = j - jh * WS7;
                int rj = (wh == 7 ? (jh < 4 ? 1 : 2) : 0) * 3 + (ww == 7 ? (jw < 4 ? 1 : 2) : 0);
                if (ri != rj) v = -100.0f;
                else v = fmaf(sacc[nt][r], SCALE, bias_s[(ih - jh + 6) * 13 + (iw - jw + 6)]);
            }
            val[r][nt] = v;
        }
    }

    #pragma unroll
    for (int r = 0; r < 4; r++) {
        float mx = fmaxf(fmaxf(val[r][0], val[r][1]), fmaxf(val[r][2], val[r][3]));
        for (int d = 1; d < 16; d <<= 1) mx = fmaxf(mx, __shfl_xor(mx, d, 64));
        float sum = 0.f;
        #pragma unroll
        for (int nt = 0; nt < 4; nt++) { float e = expf(val[r][nt] - mx); val[r][nt] = e; sum += e; }
        for (int d = 1; d < 16; d <<= 1) sum += __shfl_xor(sum, d, 64);
        float inv = 1.f / sum;
        int i = rbase + r;
        #pragma unroll
        for (int nt = 0; nt < 4; nt++)
            ps[i * 72 + nt * 16 + c] = f2b(val[r][nt] * inv);
    }

    f32x4 oacc[2] = {{}, {}};
    #pragma unroll
    for (int kh = 0; kh < 2; kh++) {
        b16x8 ap = __builtin_bit_cast(b16x8, *(const u16x8*)&ps[(wave * 16 + c) * 72 + kh * 32 + quad * 8]);
        #pragma unroll
        for (int nt = 0; nt < 2; nt++) {
            b16x8 bv = __builtin_bit_cast(b16x8, *(const u16x8*)&vsT[(nt * 16 + c) * 72 + kh * 32 + quad * 8]);
            oacc[nt] = __builtin_amdgcn_mfma_f32_16x16x32_bf16(ap, bv, oacc[nt], 0, 0, 0);
        }
    }
    #pragma unroll
    for (int nt = 0; nt < 2; nt++) {
        #pragma unroll
        for (int r = 0; r < 4; r++) {
            int i = rbase + r;
            if (i < LW)
                aout[((size_t)widx * LW + i) * CCH + head * HDIM + nt * 16 + c] = f2b(oacc[nt][r]);
        }
    }
}

extern "C" void kernel_launch(void* const* d_in, const int* in_sizes, int n_in,
                              void* d_out, int out_size, void* d_ws, size_t ws_size,
                              hipStream_t stream)
{
    const void* x_in = d_in[0];
    char* ws = (char*)d_ws;
    int* flag = (int*)ws;

    u16* qkvw_c  = (u16*)(ws + 64);
    u16* projw_c = (u16*)(ws + 221248);
    u16* fc1w_c  = (u16*)(ws + 294976);
    u16* fc2w_c  = (u16*)(ws + 589888);
    u16* n1w_c   = (u16*)(ws + 884800);
    u16* n1b_c   = (u16*)(ws + 885184);
    u16* n2w_c   = (u16*)(ws + 885568);
    u16* n2b_c   = (u16*)(ws + 885952);
    u16* projb_c = (u16*)(ws + 886336);
    u16* fc1b_c  = (u16*)(ws + 886720);
    u16* fc2b_c  = (u16*)(ws + 888256);
    u16* relb_c  = (u16*)(ws + 888640);

    const size_t P0 = 1u << 20;
    const size_t X1SZ   = (size_t)MTOK * CCH * 2;   //  38,535,168
    const size_t QKVSZ  = (size_t)MTOK * 576 * 2;   // 115,605,504
    const size_t H1FULL = (size_t)MTOK * 768 * 2;   // 154,140,672

    u16* x1 = (u16*)(ws + P0);

    probe_kernel<<<1, 1024, 0, stream>>>((const u16*)x_in, flag);
    canon_all_kernel<<<(CANON_TOTAL + 255) / 256, 256, 0, stream>>>(
        flag,
        d_in[7], d_in[9], d_in[13], d_in[15],
        d_in[5], d_in[6], d_in[11], d_in[12],
        d_in[10], d_in[14], d_in[16], d_in[8],
        ws);

    // ---- workspace tiering (round-10 verified layout).
    int QC, EC;
    u16 *aoutb, *qkvq, *h1q;
    if (ws_size >= P0 + 2 * X1SZ + H1FULL) {            // 232.3 MB
        QC = 1; EC = 1;
        aoutb = (u16*)(ws + P0 + X1SZ);
        qkvq  = (u16*)(ws + P0 + 2 * X1SZ);
        h1q   = qkvq;                                   // qkvq dead in MLP phase
    } else if (ws_size >= P0 + 2 * X1SZ + QKVSZ) {      // 193.7 MB
        QC = 1; EC = 2;
        aoutb = (u16*)(ws + P0 + X1SZ);
        qkvq  = (u16*)(ws + P0 + 2 * X1SZ);
        h1q   = qkvq;                                   // half-h1 (77MB) fits
    } else {                                            // proven 78.1 MB layout
        QC = 4; EC = 8;
        aoutb = (u16*)(ws + P0 + X1SZ);
        qkvq  = (u16*)(ws + P0 + X1SZ + 9633792);
        h1q   = (u16*)(ws + P0 + X1SZ);
    }

    const int MQ = MTOK / QC;
    const int ME = MTOK / EC;

    for (int q = 0; q < QC; q++) {
        int mb = q * MQ;
        gemm_k192<0, 9, 0><<<MQ / 64, 256, 0, stream>>>(
            nullptr, qkvw_c, 576, n1w_c, n1b_c, nullptr, qkvq, nullptr, x_in, mb, flag);
        attn_kernel<<<(NWTOT / QC) * NHEAD, 256, 0, stream>>>(qkvq, relb_c, aoutb);
        gemm_k192<1, 3, 0><<<MQ / 64, 256, 0, stream>>>(
            aoutb, projw_c, 192, nullptr, nullptr, projb_c, nullptr, x1, x_in, mb, flag);
    }

    for (int e = 0; e < EC; e++) {
        size_t off = (size_t)e * ME * CCH;
        gemm_k192<2, 12, 1><<<ME / 64, 256, 0, stream>>>(
            x1 + off, fc1w_c, 768, n2w_c, n2b_c, fc1b_c, h1q, nullptr, nullptr, 0, flag);
        gemm_t3<768><<<dim3(ME / 128, 1), 256, 0, stream>>>(
            h1q, fc2w_c, fc2b_c, x1 + off, d_out, off, flag);
    }
}

// Round 13
// 562.239 us; speedup vs baseline: 1.0453x; 1.0161x over previous
//
#include <hip/hip_runtime.h>

#define WS7    7
#define SHIFT3 3
#define NHEAD  6
#define CCH    192
#define HDIM   32
#define HH56   56
#define LTOK   (HH56*HH56)      // 3136
#define NWIN   64
#define NBATCH 32
#define NWTOT  (NBATCH*NWIN)    // 2048
#define LW     49
#define MTOK   (NWTOT*LW)       // 100352

typedef unsigned short u16;
typedef unsigned int   u32;
typedef __bf16 b16;
typedef b16   b16x8 __attribute__((ext_vector_type(8)));
typedef u16   u16x8 __attribute__((ext_vector_type(8)));
typedef float f32x4 __attribute__((ext_vector_type(4)));

__device__ __forceinline__ float b2f(u16 u) {
    u32 x = ((u32)u) << 16;
    return __builtin_bit_cast(float, x);
}
__device__ __forceinline__ u16 f2b(float f) {
    u32 x = __builtin_bit_cast(u32, f);
    u32 r = x + 0x7FFFu + ((x >> 16) & 1u);
    return (u16)(r >> 16);
}
// Fast exact-accuracy gelu (A&S 7.1.26 erf, |err|<1.5e-7 < bf16 quantum).
__device__ __forceinline__ float gelu_exact(float x) {
    float z  = x * 0.7071067811865475f;
    float az = fabsf(z);
    float t  = __fdividef(1.0f, fmaf(0.3275911f, az, 1.0f));
    float p  = t * fmaf(t, fmaf(t, fmaf(t, fmaf(t, 1.061405429f, -1.453152027f),
                        1.421413741f), -0.284496736f), 0.254829592f);
    float e  = __expf(-az * az);
    float erfv = copysignf(fmaf(-p, e, 1.0f), z);
    return 0.5f * x * (1.0f + erfv);
}

// token m (window-order) -> (b, l) image order (bijection)
__device__ __forceinline__ int map_token(int m, int &b) {
    int widx = m / LW, p = m - widx * LW;
    b = widx >> 6;
    int wloc = widx & 63;
    int wh = wloc >> 3, ww = wloc & 7;
    int i = p / WS7, j = p - i * WS7;
    int gh = wh * WS7 + i + SHIFT3; if (gh >= HH56) gh -= HH56;
    int gw = ww * WS7 + j + SHIFT3; if (gw >= HH56) gw -= HH56;
    return gh * HH56 + gw;
}

// ---- dtype probe: flag=1 if x is fp32 storage, 0 if bf16 storage.
__global__ __launch_bounds__(1024) void probe_kernel(const u16* __restrict__ x, int* flag) {
    __shared__ int ch, cz;
    if (threadIdx.x == 0) { ch = 0; cz = 0; }
    __syncthreads();
    int i = threadIdx.x * 16;
    u16x8 a = *(const u16x8*)(x + i);
    u16x8 b = *(const u16x8*)(x + i + 8);
    int h = 0, z = 0;
    #pragma unroll
    for (int q = 0; q < 8; q++) {
        h += (((a[q] >> 7) & 0xFF) >= 0xC0) + (((b[q] >> 7) & 0xFF) >= 0xC0);
        z += (a[q] == 0) + (b[q] == 0);
    }
    #pragma unroll
    for (int off = 32; off > 0; off >>= 1) {
        h += __shfl_xor(h, off, 64);
        z += __shfl_xor(z, off, 64);
    }
    if ((threadIdx.x & 63) == 0) { atomicAdd(&ch, h); atomicAdd(&cz, z); }
    __syncthreads();
    if (threadIdx.x == 0) *flag = (ch > 250 || cz > 2048) ? 1 : 0;
}

// ---- canonicalize ALL param tensors to bf16 in ONE launch.
#define CANON_TOTAL 445302
__global__ __launch_bounds__(256) void canon_all_kernel(
    const int* __restrict__ flag,
    const void* s0, const void* s1, const void* s2,  const void* s3,
    const void* s4, const void* s5, const void* s6,  const void* s7,
    const void* s8, const void* s9, const void* s10, const void* s11,
    char* __restrict__ ws)
{
    int i = blockIdx.x * 256 + threadIdx.x;
    if (i >= CANON_TOTAL) return;
    const void* srcs[12] = {s0, s1, s2, s3, s4, s5, s6, s7, s8, s9, s10, s11};
    const int cnt[12] = {110592, 36864, 147456, 147456, 192, 192, 192, 192, 192, 768, 192, 1014};
    const int off[12] = {64, 221248, 294976, 589888, 884800, 885184, 885568, 885952, 886336, 886720, 888256, 888640};
    int seg = 0, base = 0;
    while (seg < 11 && i >= base + cnt[seg]) { base += cnt[seg]; seg++; }
    int j = i - base;
    const void* sp = srcs[seg];
    u16* dp = (u16*)(ws + off[seg]);
    dp[j] = (*flag) ? f2b(((const float*)sp)[j]) : ((const u16*)sp)[j];
}

// ---- DMA-stage a ROWSx32 bf16 chunk (row stride ldk u16) into LINEAR LDS
// [ROWS][32] with chunk swizzle (lds slot c holds global quad c^((row>>1)&3);
// pre-swizzled global source, same XOR on read). Uniform ROWS*4/256 loads/thread.
template<int ROWS>
__device__ __forceinline__ void stageL(const u16* __restrict__ g, int ldk, u16* s, int tid) {
    constexpr int ITER = ROWS * 4 / 256;
    #pragma unroll
    for (int it = 0; it < ITER; it++) {
        int t = it * 256 + tid;
        int row = t >> 2, c = t & 3;
        int cc = c ^ ((row >> 1) & 3);
        const u16* src = g + (size_t)row * ldk + cc * 8;
        u16* dst = s + (size_t)(it * 256 + (tid & ~63)) * 8;   // wave base
        __builtin_amdgcn_global_load_lds(
            (const __attribute__((address_space(1))) void*)src,
            (__attribute__((address_space(3))) void*)dst, 16, 0, 0);
    }
}

// ---- swizzled-layout address of 8-col group idx (cols idx*8..idx*8+7) of row r
// within a 6-chunk [64][32] swizzled A/B region.
__device__ __forceinline__ int swz_addr(int r, int idx) {
    int ks = idx >> 2, q = idx & 3;
    return ks * 2048 + r * 32 + ((q ^ ((r >> 1) & 3)) * 8);
}

// ---- in-LDS LayerNorm of a swizzled 64x192 tile (6 chunks of [64][32]).
// Thread (r=tid>>2, p=tid&3) handles cols p*48..p*48+47 (groups idx=6p+j).
__device__ __forceinline__ void ln_swz(u16* As, const u16* __restrict__ w,
                                       const u16* __restrict__ bia, int tid) {
    int r = tid >> 2, p = tid & 3;
    u16x8 vv[6];
    float s = 0.f, sq = 0.f;
    #pragma unroll
    for (int j = 0; j < 6; j++) {
        vv[j] = *(const u16x8*)&As[swz_addr(r, p * 6 + j)];
        #pragma unroll
        for (int q = 0; q < 8; q++) { float f = b2f(vv[j][q]); s += f; sq += f * f; }
    }
    s  += __shfl_xor(s, 1, 64);  s  += __shfl_xor(s, 2, 64);
    sq += __shfl_xor(sq, 1, 64); sq += __shfl_xor(sq, 2, 64);
    float mean = s * (1.f / 192.f);
    float var  = fmaxf(sq * (1.f / 192.f) - mean * mean, 0.f);
    float rstd = rsqrtf(var + 1e-5f);
    #pragma unroll
    for (int j = 0; j < 6; j++) {
        u16x8 o;
        #pragma unroll
        for (int q = 0; q < 8; q++) {
            int col = p * 48 + j * 8 + q;
            o[q] = f2b((b2f(vv[j][q]) - mean) * rstd * b2f(w[col]) + b2f(bia[col]));
        }
        *(u16x8*)&As[swz_addr(r, p * 6 + j)] = o;
    }
}

// ---- Fused LN1 A-stage for qkv: gather 64 window-order rows of x via
// map_token, LayerNorm in registers (4 threads/row, shfl_xor(1,2) reduce),
// write bf16 into the SWIZZLED 6-chunk A layout.
__device__ __forceinline__ void gather_ln_swz(const void* __restrict__ xsrc, int isf,
                                              int mtile, const u16* __restrict__ w,
                                              const u16* __restrict__ bia,
                                              u16* As, int tid) {
    int r = tid >> 2, p = tid & 3;
    int b; int l = map_token(mtile + r, b);
    size_t rowoff = ((size_t)b * LTOK + l) * CCH + p * 48;
    float v[48];
    if (isf) {
        const float* xp = (const float*)xsrc + rowoff;
        #pragma unroll
        for (int j = 0; j < 12; j++) {
            float4 f = *(const float4*)(xp + j * 4);
            v[j * 4 + 0] = f.x; v[j * 4 + 1] = f.y;
            v[j * 4 + 2] = f.z; v[j * 4 + 3] = f.w;
        }
    } else {
        const u16* xp = (const u16*)xsrc + rowoff;
        #pragma unroll
        for (int j = 0; j < 6; j++) {
            u16x8 u = *(const u16x8*)(xp + j * 8);
            #pragma unroll
            for (int q = 0; q < 8; q++) v[j * 8 + q] = b2f(u[q]);
        }
    }
    float s = 0.f, sq = 0.f;
    #pragma unroll
    for (int j = 0; j < 48; j++) { s += v[j]; sq += v[j] * v[j]; }
    s  += __shfl_xor(s, 1, 64);  s  += __shfl_xor(s, 2, 64);
    sq += __shfl_xor(sq, 1, 64); sq += __shfl_xor(sq, 2, 64);
    float mean = s * (1.f / 192.f);
    float var  = fmaxf(sq * (1.f / 192.f) - mean * mean, 0.f);
    float rstd = rsqrtf(var + 1e-5f);
    #pragma unroll
    for (int j = 0; j < 6; j++) {
        u16x8 o;
        #pragma unroll
        for (int q = 0; q < 8; q++) {
            int col = p * 48 + j * 8 + q;
            o[q] = f2b((v[j * 8 + q] - mean) * rstd * b2f(w[col]) + b2f(bia[col]));
        }
        *(u16x8*)&As[swz_addr(r, p * 6 + j)] = o;
    }
}

// ---- GEMM K=192 (round-10 verified sync structure, SWIZZLED-LINEAR LDS):
// A tile staged ONCE (6x [64][32] chunks, 0-conflict reads like gemm_t3),
// NT 64-wide n-tiles streamed through a double-buffered swizzled B stage.
// 24 MFMA per barrier. LDS 73.7KB -> 2 blocks/CU (same as before).
// MODE 0: qkv with FUSED LN1-gather A-stage. MODE 1: proj + residual scatter.
// MODE 2: fc1 + gelu, LNF=1 applies LN2 to staged A in LDS.
template<int MODE, int NT, int LNF>
__global__ __launch_bounds__(256) void gemm_k192s(
    const u16* __restrict__ A, const u16* __restrict__ Bm, int N,
    const u16* __restrict__ lnw, const u16* __restrict__ lnb,
    const u16* __restrict__ bias,
    u16* __restrict__ Cb, u16* __restrict__ X1, const void* __restrict__ Xin,
    int m_base, const int* __restrict__ flag)
{
    __shared__ __align__(16) u16 As[6 * 64 * 32];
    __shared__ __align__(16) u16 Bs[2][6 * 64 * 32];
    int isf = *flag;
    int tid = threadIdx.x;
    int m0 = blockIdx.x * 64;
    int wave = tid >> 6, lane = tid & 63;
    int wm = wave >> 1, wn = wave & 1;
    int quad = lane >> 4, mr = lane & 15;

    // B tile 0 staging overlaps A prologue
    #pragma unroll
    for (int ks = 0; ks < 6; ks++)
        stageL<64>(Bm + ks * 32, 192, Bs[0] + ks * 2048, tid);
    if (MODE == 0) {
        gather_ln_swz(Xin, isf, m_base + m0, lnw, lnb, As, tid);
    } else {
        #pragma unroll
        for (int ks = 0; ks < 6; ks++)
            stageL<64>(A + (size_t)m0 * 192 + ks * 32, 192, As + ks * 2048, tid);
    }
    __syncthreads();
    if (LNF) { ln_swz(As, lnw, lnb, tid); __syncthreads(); }

    int rowA0 = wm * 32 + mr;
    int rowB0 = wn * 32 + mr;
    int pa0 = rowA0 * 32 + ((quad ^ ((rowA0 >> 1) & 3)) * 8);   // +512 for row+16
    int pb0 = rowB0 * 32 + ((quad ^ ((rowB0 >> 1) & 3)) * 8);

    #pragma unroll 1
    for (int nb = 0; nb < NT; nb++) {
        if (nb + 1 < NT) {
            #pragma unroll
            for (int ks = 0; ks < 6; ks++)
                stageL<64>(Bm + (size_t)(nb + 1) * 64 * 192 + ks * 32, 192,
                           Bs[(nb + 1) & 1] + ks * 2048, tid);
        }
        const u16* bsb = Bs[nb & 1];
        f32x4 acc00 = {}, acc01 = {}, acc10 = {}, acc11 = {};
        #pragma unroll
        for (int ks = 0; ks < 6; ks++) {
            b16x8 a0 = __builtin_bit_cast(b16x8, *(const u16x8*)&As[ks * 2048 + pa0]);
            b16x8 a1 = __builtin_bit_cast(b16x8, *(const u16x8*)&As[ks * 2048 + pa0 + 512]);
            b16x8 b0 = __builtin_bit_cast(b16x8, *(const u16x8*)&bsb[ks * 2048 + pb0]);
            b16x8 b1 = __builtin_bit_cast(b16x8, *(const u16x8*)&bsb[ks * 2048 + pb0 + 512]);
            acc00 = __builtin_amdgcn_mfma_f32_16x16x32_bf16(a0, b0, acc00, 0, 0, 0);
            acc01 = __builtin_amdgcn_mfma_f32_16x16x32_bf16(a0, b1, acc01, 0, 0, 0);
            acc10 = __builtin_amdgcn_mfma_f32_16x16x32_bf16(a1, b0, acc10, 0, 0, 0);
            acc11 = __builtin_amdgcn_mfma_f32_16x16x32_bf16(a1, b1, acc11, 0, 0, 0);
        }
        int n0 = nb * 64;
        f32x4 accs[2][2] = {{acc00, acc01}, {acc10, acc11}};
        #pragma unroll
        for (int sm = 0; sm < 2; sm++) {
            #pragma unroll
            for (int sn = 0; sn < 2; sn++) {
                f32x4 v = accs[sm][sn];
                int nn = n0 + wn * 32 + sn * 16 + mr;
                int mb = m0 + wm * 32 + sm * 16 + quad * 4;
                #pragma unroll
                for (int r = 0; r < 4; r++) {
                    int mm = mb + r;
                    float val = v[r];
                    if (MODE == 0) {
                        Cb[(size_t)mm * N + nn] = f2b(val);
                    } else if (MODE == 1) {
                        val += b2f(bias[nn]);
                        int b; int l = map_token(m_base + mm, b);
                        size_t idx = ((size_t)b * LTOK + l) * CCH + nn;
                        float xi = isf ? ((const float*)Xin)[idx] : b2f(((const u16*)Xin)[idx]);
                        X1[idx] = f2b(xi + val);
                    } else {
                        val = gelu_exact(val + b2f(bias[nn]));
                        Cb[(size_t)mm * N + nn] = f2b(val);
                    }
                }
            }
        }
        __syncthreads();   // B(nb+1) DMA drained; Bs[nb&1] free for re-stage
    }
}

// ---- fc2 GEMM (round-7 verified, 0 conflicts): 128M x 192N, BK=32,
// 2 LDS buffers (40.6KB -> 3 blocks/CU), counted vmcnt(5) pipeline.
// Epilogue: gelu + bias + residual(X1) -> Oout (dtype per flag).
template<int KK>
__global__ __launch_bounds__(256, 3) void gemm_t3(
    const u16* __restrict__ A, const u16* __restrict__ Bm,
    const u16* __restrict__ bias,
    const u16* __restrict__ X1,
    void* __restrict__ Oout, size_t o_off,
    const int* __restrict__ flag)
{
    __shared__ __align__(16) u16 As[2][128 * 32];
    __shared__ __align__(16) u16 Bs[2][192 * 32];
    int tid = threadIdx.x;
    int m0 = blockIdx.x * 128, n0 = blockIdx.y * 192;
    int wave = tid >> 6, lane = tid & 63;
    int wm = wave >> 1, wn = wave & 1;
    int quad = lane >> 4, mr = lane & 15;

    const u16* Ag = A + (size_t)m0 * KK;
    const u16* Bg = Bm + (size_t)n0 * KK;

    stageL<128>(Ag, KK, As[0], tid);
    stageL<192>(Bg, KK, Bs[0], tid);

    f32x4 acc[4][6] = {};
    constexpr int NSTEP = KK / 32;

    #pragma unroll 1
    for (int t = 0; t < NSTEP; t++) {
        int cur = t & 1;
        if (t + 1 < NSTEP) {
            stageL<128>(Ag + (t + 1) * 32, KK, As[cur ^ 1], tid);
            stageL<192>(Bg + (t + 1) * 32, KK, Bs[cur ^ 1], tid);
            asm volatile("s_waitcnt vmcnt(5)");   // stage(t) landed; 5 in flight
        } else {
            asm volatile("s_waitcnt vmcnt(0)");   // last step: full drain
        }
        __builtin_amdgcn_s_barrier();
        __builtin_amdgcn_sched_barrier(0);
        b16x8 a[4], b[6];
        #pragma unroll
        for (int sm = 0; sm < 4; sm++) {
            int row = wm * 64 + sm * 16 + mr;
            a[sm] = __builtin_bit_cast(b16x8,
                *(const u16x8*)&As[cur][row * 32 + (quad ^ ((row >> 1) & 3)) * 8]);
        }
        #pragma unroll
        for (int sn = 0; sn < 6; sn++) {
            int row = wn * 96 + sn * 16 + mr;
            b[sn] = __builtin_bit_cast(b16x8,
                *(const u16x8*)&Bs[cur][row * 32 + (quad ^ ((row >> 1) & 3)) * 8]);
        }
        #pragma unroll
        for (int sm = 0; sm < 4; sm++)
            #pragma unroll
            for (int sn = 0; sn < 6; sn++)
                acc[sm][sn] = __builtin_amdgcn_mfma_f32_16x16x32_bf16(a[sm], b[sn], acc[sm][sn], 0, 0, 0);
        __builtin_amdgcn_sched_barrier(0);
        __builtin_amdgcn_s_barrier();             // protect buf before re-stage
    }

    int isf = *flag;
    #pragma unroll
    for (int sm = 0; sm < 4; sm++) {
        #pragma unroll
        for (int r = 0; r < 4; r++) {
            int mm = m0 + wm * 64 + sm * 16 + quad * 4 + r;
            #pragma unroll
            for (int sn = 0; sn < 6; sn++) {
                int nn = n0 + wn * 96 + sn * 16 + mr;
                float val = gelu_exact(acc[sm][sn][r] + b2f(bias[nn]));
                size_t idx = (size_t)mm * CCH + nn;
                float r2 = val + b2f(X1[idx]);
                if (isf) ((float*)Oout)[o_off + idx] = r2;
                else     ((u16*)Oout)[o_off + idx]  = f2b(r2);
            }
        }
    }
}

// ---- MFMA attention (unchanged, verified)
__global__ __launch_bounds__(256) void attn_kernel(
    const u16* __restrict__ qkv, const u16* __restrict__ rel_bias,
    u16* __restrict__ aout)
{
    __shared__ __align__(16) u16 qs[64 * 32];
    __shared__ __align__(16) u16 ks[64 * 32];
    __shared__ __align__(16) u16 vsT[32 * 72];
    __shared__ __align__(16) u16 ps[64 * 72];
    __shared__ float bias_s[169];
    int blk = blockIdx.x;
    int widx = blk / NHEAD, head = blk - widx * NHEAD;
    int wloc = widx & 63;
    int wh = wloc >> 3, ww = wloc & 7;
    int tid = threadIdx.x;
    const u16* base = qkv + (size_t)widx * LW * 576 + head * HDIM;

    if (tid < 196) {
        int i = tid >> 2, c8 = (tid & 3) * 8;
        *(uint4*)&qs[i * 32 + c8] = *(const uint4*)(base + (size_t)i * 576 + c8);
        *(uint4*)&ks[i * 32 + c8] = *(const uint4*)(base + (size_t)i * 576 + 192 + c8);
        u16x8 vv = *(const u16x8*)(base + (size_t)i * 576 + 384 + c8);
        #pragma unroll
        for (int q = 0; q < 8; q++) vsT[(c8 + q) * 72 + i] = vv[q];
    }
    for (int idx = tid; idx < 32 * 15; idx += 256) {   // zero pad cols 49..63
        int d = idx / 15, j = 49 + (idx - d * 15);
        vsT[d * 72 + j] = 0;
    }
    if (tid < 169) bias_s[tid] = b2f(rel_bias[tid * NHEAD + head]);
    __syncthreads();

    int wave = tid >> 6, lane = tid & 63;
    int quad = lane >> 4, c = lane & 15;

    b16x8 aq = __builtin_bit_cast(b16x8, *(const u16x8*)&qs[(wave * 16 + c) * 32 + quad * 8]);
    f32x4 sacc[4];
    #pragma unroll
    for (int nt = 0; nt < 4; nt++) {
        b16x8 bk = __builtin_bit_cast(b16x8, *(const u16x8*)&ks[(nt * 16 + c) * 32 + quad * 8]);
        f32x4 z = {};
        sacc[nt] = __builtin_amdgcn_mfma_f32_16x16x32_bf16(aq, bk, z, 0, 0, 0);
    }

    const float SCALE = 13.856406460551018f;
    float val[4][4];
    int rbase = wave * 16 + quad * 4;
    #pragma unroll
    for (int r = 0; r < 4; r++) {
        int i = rbase + r;
        int ih = i / WS7, iw = i - ih * WS7;
        int ri = (wh == 7 ? (ih < 4 ? 1 : 2) : 0) * 3 + (ww == 7 ? (iw < 4 ? 1 : 2) : 0);
        #pragma unroll
        for (int nt = 0; nt < 4; nt++) {
            int j = nt * 16 + c;
            float v;
            if (i >= LW) v = 0.f;
            else if (j >= LW) v = -1e30f;
            else {
                int jh = j / WS7, jw = j - jh * WS7;
                int rj = (wh == 7 ? (jh < 4 ? 1 : 2) : 0) * 3 + (ww == 7 ? (jw < 4 ? 1 : 2) : 0);
                if (ri != rj) v = -100.0f;
                else v = fmaf(sacc[nt][r], SCALE, bias_s[(ih - jh + 6) * 13 + (iw - jw + 6)]);
            }
            val[r][nt] = v;
        }
    }

    #pragma unroll
    for (int r = 0; r < 4; r++) {
        float mx = fmaxf(fmaxf(val[r][0], val[r][1]), fmaxf(val[r][2], val[r][3]));
        for (int d = 1; d < 16; d <<= 1) mx = fmaxf(mx, __shfl_xor(mx, d, 64));
        float sum = 0.f;
        #pragma unroll
        for (int nt = 0; nt < 4; nt++) { float e = expf(val[r][nt] - mx); val[r][nt] = e; sum += e; }
        for (int d = 1; d < 16; d <<= 1) sum += __shfl_xor(sum, d, 64);
        float inv = 1.f / sum;
        int i = rbase + r;
        #pragma unroll
        for (int nt = 0; nt < 4; nt++)
            ps[i * 72 + nt * 16 + c] = f2b(val[r][nt] * inv);
    }

    f32x4 oacc[2] = {{}, {}};
    #pragma unroll
    for (int kh = 0; kh < 2; kh++) {
        b16x8 ap = __builtin_bit_cast(b16x8, *(const u16x8*)&ps[(wave * 16 + c) * 72 + kh * 32 + quad * 8]);
        #pragma unroll
        for (int nt = 0; nt < 2; nt++) {
            b16x8 bv = __builtin_bit_cast(b16x8, *(const u16x8*)&vsT[(nt * 16 + c) * 72 + kh * 32 + quad * 8]);
            oacc[nt] = __builtin_amdgcn_mfma_f32_16x16x32_bf16(ap, bv, oacc[nt], 0, 0, 0);
        }
    }
    #pragma unroll
    for (int nt = 0; nt < 2; nt++) {
        #pragma unroll
        for (int r = 0; r < 4; r++) {
            int i = rbase + r;
            if (i < LW)
                aout[((size_t)widx * LW + i) * CCH + head * HDIM + nt * 16 + c] = f2b(oacc[nt][r]);
        }
    }
}

extern "C" void kernel_launch(void* const* d_in, const int* in_sizes, int n_in,
                              void* d_out, int out_size, void* d_ws, size_t ws_size,
                              hipStream_t stream)
{
    const void* x_in = d_in[0];
    char* ws = (char*)d_ws;
    int* flag = (int*)ws;

    u16* qkvw_c  = (u16*)(ws + 64);
    u16* projw_c = (u16*)(ws + 221248);
    u16* fc1w_c  = (u16*)(ws + 294976);
    u16* fc2w_c  = (u16*)(ws + 589888);
    u16* n1w_c   = (u16*)(ws + 884800);
    u16* n1b_c   = (u16*)(ws + 885184);
    u16* n2w_c   = (u16*)(ws + 885568);
    u16* n2b_c   = (u16*)(ws + 885952);
    u16* projb_c = (u16*)(ws + 886336);
    u16* fc1b_c  = (u16*)(ws + 886720);
    u16* fc2b_c  = (u16*)(ws + 888256);
    u16* relb_c  = (u16*)(ws + 888640);

    const size_t P0 = 1u << 20;
    const size_t X1SZ   = (size_t)MTOK * CCH * 2;   //  38,535,168
    const size_t QKVSZ  = (size_t)MTOK * 576 * 2;   // 115,605,504
    const size_t H1FULL = (size_t)MTOK * 768 * 2;   // 154,140,672

    u16* x1 = (u16*)(ws + P0);

    probe_kernel<<<1, 1024, 0, stream>>>((const u16*)x_in, flag);
    canon_all_kernel<<<(CANON_TOTAL + 255) / 256, 256, 0, stream>>>(
        flag,
        d_in[7], d_in[9], d_in[13], d_in[15],
        d_in[5], d_in[6], d_in[11], d_in[12],
        d_in[10], d_in[14], d_in[16], d_in[8],
        ws);

    // ---- workspace tiering (round-10 verified layout).
    int QC, EC;
    u16 *aoutb, *qkvq, *h1q;
    if (ws_size >= P0 + 2 * X1SZ + H1FULL) {            // 232.3 MB
        QC = 1; EC = 1;
        aoutb = (u16*)(ws + P0 + X1SZ);
        qkvq  = (u16*)(ws + P0 + 2 * X1SZ);
        h1q   = qkvq;                                   // qkvq dead in MLP phase
    } else if (ws_size >= P0 + 2 * X1SZ + QKVSZ) {      // 193.7 MB
        QC = 1; EC = 2;
        aoutb = (u16*)(ws + P0 + X1SZ);
        qkvq  = (u16*)(ws + P0 + 2 * X1SZ);
        h1q   = qkvq;                                   // half-h1 (77MB) fits
    } else {                                            // proven 78.1 MB layout
        QC = 4; EC = 8;
        aoutb = (u16*)(ws + P0 + X1SZ);
        qkvq  = (u16*)(ws + P0 + X1SZ + 9633792);
        h1q   = (u16*)(ws + P0 + X1SZ);
    }

    const int MQ = MTOK / QC;
    const int ME = MTOK / EC;

    for (int q = 0; q < QC; q++) {
        int mb = q * MQ;
        gemm_k192s<0, 9, 0><<<MQ / 64, 256, 0, stream>>>(
            nullptr, qkvw_c, 576, n1w_c, n1b_c, nullptr, qkvq, nullptr, x_in, mb, flag);
        attn_kernel<<<(NWTOT / QC) * NHEAD, 256, 0, stream>>>(qkvq, relb_c, aoutb);
        gemm_k192s<1, 3, 0><<<MQ / 64, 256, 0, stream>>>(
            aoutb, projw_c, 192, nullptr, nullptr, projb_c, nullptr, x1, x_in, mb, flag);
    }

    for (int e = 0; e < EC; e++) {
        size_t off = (size_t)e * ME * CCH;
        gemm_k192s<2, 12, 1><<<ME / 64, 256, 0, stream>>>(
            x1 + off, fc1w_c, 768, n2w_c, n2b_c, fc1b_c, h1q, nullptr, nullptr, 0, flag);
        gemm_t3<768><<<dim3(ME / 128, 1), 256, 0, stream>>>(
            h1q, fc2w_c, fc2b_c, x1 + off, d_out, off, flag);
    }
}